// Round 10
// baseline (517.104 us; speedup 1.0000x reference)
//
#include <hip/hip_runtime.h>
#include <hip/hip_bf16.h>
#include <hip/hip_cooperative_groups.h>

namespace cooperative_groups_ns = cooperative_groups;

#define HW 131072      // h*w
#define NCH 128        // channels
#define KS 9
#define L_TOTAL 163840 // Q*M*M
#define NGRP 8         // channel groups == XCDs
#define LPB 256        // l's per gather tile

typedef float        f32x2 __attribute__((ext_vector_type(2)));
typedef float        f32x4 __attribute__((ext_vector_type(4)));
typedef unsigned int u32x2 __attribute__((ext_vector_type(2)));
typedef unsigned int u32x4 __attribute__((ext_vector_type(4)));

static __device__ __forceinline__ float bflo(unsigned int p) { return __uint_as_float(p << 16); }
static __device__ __forceinline__ float bfhi(unsigned int p) { return __uint_as_float(p & 0xffff0000u); }
static __device__ __forceinline__ unsigned short f2bf(float f) {
    unsigned int x = __float_as_uint(f);
    return (unsigned short)((x + 0x7fffu + ((x >> 16) & 1u)) >> 16);  // RNE
}

// ---------------------------------------------------------------------------
// Kernel 1: transpose (2 p-tiles) [+ grid.sync] + mult (320 l's).
// mode: 0 = transpose only, 1 = mult only, 2 = both with grid.sync (coop).
// Grid 512 x 256. LDS 36864 B -> 2 blocks/CU co-residency with 2x margin.
// ---------------------------------------------------------------------------
__global__ __launch_bounds__(256, 2) void prep_kernel(
    const f32x4* __restrict__ xf4,        // x: [NCH][HW/4] float4 along p
    unsigned int* __restrict__ xT,        // [8][HW][8] dword slabs
    float2* __restrict__ meanmaxP,        // [HW] (mean, max) over channels
    const int* __restrict__ cks,          // [L][9]
    const float* __restrict__ att_w,      // [9][2][9]
    const float* __restrict__ att_b,      // [9]
    unsigned int* __restrict__ rec,       // [L][12] packed idx|mult
    float* __restrict__ gz,               // gsum(128)+gsq(128) to zero
    int mode)
{
    __shared__ __align__(16) char smem[36864];
    const int tid = threadIdx.x;

    // ================= Phase A: transpose =================
    if (mode != 1) {
        unsigned short* tile = (unsigned short*)smem;        // [0, 32768)
        float* ps = (float*)(smem + 32768);                  // [4][128]
        float* pm = (float*)(smem + 34816);                  // [4][128]
        const int pj = tid & 31;          // f32x4 slot -> p's 4pj..4pj+3
        const int cgi = tid >> 5;         // c-group (8 groups)
        const int wave = tid >> 6;

        if (blockIdx.x == 0) gz[tid] = 0.f;

        for (int tt = 0; tt < 2; ++tt) {
            const int p0 = (blockIdx.x * 2 + tt) * 128;

            float s0 = 0.f, s1 = 0.f, s2 = 0.f, s3 = 0.f;
            float m0 = -3.4e38f, m1 = -3.4e38f, m2 = -3.4e38f, m3 = -3.4e38f;
            #pragma unroll 4
            for (int it = 0; it < 16; ++it) {
                const int c = cgi + (it << 3);
                const f32x4 v = __builtin_nontemporal_load(
                    &xf4[(long)c * (HW / 4) + (p0 >> 2) + pj]);
                const int pA = 4 * pj;
                tile[(pA + 0) * 128 + ((c + 2 * (pA + 0)) & 127)] = f2bf(v.x);
                tile[(pA + 1) * 128 + ((c + 2 * (pA + 1)) & 127)] = f2bf(v.y);
                tile[(pA + 2) * 128 + ((c + 2 * (pA + 2)) & 127)] = f2bf(v.z);
                tile[(pA + 3) * 128 + ((c + 2 * (pA + 3)) & 127)] = f2bf(v.w);
                s0 += v.x; s1 += v.y; s2 += v.z; s3 += v.w;
                m0 = fmaxf(m0, v.x); m1 = fmaxf(m1, v.y);
                m2 = fmaxf(m2, v.z); m3 = fmaxf(m3, v.w);
            }
            // fold c-group pairs (tid ^ 32) -> partials shrink to [4][128]
            s0 += __shfl_xor(s0, 32); s1 += __shfl_xor(s1, 32);
            s2 += __shfl_xor(s2, 32); s3 += __shfl_xor(s3, 32);
            m0 = fmaxf(m0, __shfl_xor(m0, 32)); m1 = fmaxf(m1, __shfl_xor(m1, 32));
            m2 = fmaxf(m2, __shfl_xor(m2, 32)); m3 = fmaxf(m3, __shfl_xor(m3, 32));
            if ((tid & 32) == 0) {
                const int pA = 4 * pj;
                ps[wave * 128 + pA + 0] = s0; ps[wave * 128 + pA + 1] = s1;
                ps[wave * 128 + pA + 2] = s2; ps[wave * 128 + pA + 3] = s3;
                pm[wave * 128 + pA + 0] = m0; pm[wave * 128 + pA + 1] = m1;
                pm[wave * 128 + pA + 2] = m2; pm[wave * 128 + pA + 3] = m3;
            }
            __syncthreads();

            // store: idx2 -> (slab s, p, dword-pair); wave = 512 B contiguous.
            #pragma unroll 4
            for (int it = 0; it < 16; ++it) {
                const int idx2 = it * 256 + tid;       // [0, 4096) u32x2 units
                const int s = idx2 >> 9;               // slab (512 u32x2 each)
                const int rem = idx2 & 511;
                const int p = rem >> 2;
                const int dp = rem & 3;
                const int cpair = s * 8 + 2 * dp;
                const int col0 = (2 * cpair + 2 * p) & 127;
                const int col1 = (2 * cpair + 2 + 2 * p) & 127;
                u32x2 u;
                u.x = *reinterpret_cast<const unsigned int*>(&tile[p * 128 + col0]);
                u.y = *reinterpret_cast<const unsigned int*>(&tile[p * 128 + col1]);
                *(u32x2*)&xT[((long)s * HW + (p0 + p)) * 8 + 2 * dp] = u;
            }
            if (tid < 128) {
                float s = ps[0 * 128 + tid] + ps[1 * 128 + tid]
                        + ps[2 * 128 + tid] + ps[3 * 128 + tid];
                float m = fmaxf(fmaxf(pm[0 * 128 + tid], pm[1 * 128 + tid]),
                                fmaxf(pm[2 * 128 + tid], pm[3 * 128 + tid]));
                meanmaxP[p0 + tid] = make_float2(s * 0.0078125f, m);
            }
            __syncthreads();   // tile consumed; safe for next tt / phase B
        }
    }

    if (mode == 2)
        cooperative_groups_ns::this_grid().sync();  // meanmaxP device-visible

    // ================= Phase B: mult (320 l's per block) =================
    if (mode != 0) {
        float* attw = (float*)smem;                          // 162 f
        float* attb = (float*)(smem + 648);                  // 12 f -> 704
        unsigned int* lrec = (unsigned int*)(smem + 704);    // 320*12 u32 = 15360 B
        const int base_l = blockIdx.x * 320;

        if (tid < 162) attw[tid] = att_w[tid];
        if (tid < KS) attb[tid] = att_b[tid];
        for (int j = tid; j < 320 * KS; j += 256) {
            const int lj = j / KS;
            lrec[lj * 12 + (j - lj * KS)] = (unsigned int)cks[(long)base_l * KS + j];
        }
        __syncthreads();

        for (int lb = 0; lb < 320; lb += 256) {
            const int ll = lb + tid;
            if (ll < 320) {
                unsigned int idx[KS];
                float mean[KS], mx[KS];
                #pragma unroll
                for (int k = 0; k < KS; ++k) {
                    idx[k] = lrec[ll * 12 + k];
                    const float2 mm = meanmaxP[idx[k]];
                    mean[k] = mm.x; mx[k] = mm.y;
                }
                #pragma unroll
                for (int o = 0; o < KS; ++o) {
                    float logit = attb[o];
                    #pragma unroll
                    for (int k = 0; k < KS; ++k) {
                        logit = fmaf(mean[k], attw[o * 18 + k], logit);
                        logit = fmaf(mx[k],   attw[o * 18 + 9 + k], logit);
                    }
                    const float sig = 1.0f / (1.0f + __expf(-logit));
                    unsigned int u = (unsigned int)(sig * 32768.0f + 0.5f);
                    if (u > 32767u) u = 32767u;
                    lrec[ll * 12 + o] = idx[o] | (u << 17);
                }
            }
        }
        __syncthreads();

        // coalesced flush: 3840 dwords = 960 u32x4
        const u32x4* lv = (const u32x4*)lrec;
        u32x4* dst = (u32x4*)(rec + (size_t)base_l * 12);
        for (int j = tid; j < 960; j += 256)
            dst[j] = lv[j];
    }
}

// ---------------------------------------------------------------------------
// Kernel 2: gather (5 tiles, XCD-sliced) [+ grid.sync] + finalize.
// mode: 0 = gather only, 1 = finalize only, 2 = both with grid.sync (coop).
// Grid 1024 x 256, LDS ~9.7 KB, VGPR<=128 -> 4 blocks/CU.
// ---------------------------------------------------------------------------
__global__ __launch_bounds__(256, 4) void gatherfin_kernel(
    const unsigned int* __restrict__ xT,       // [8][HW][8]
    const unsigned int* __restrict__ rec,      // [L][12] packed
    const float* __restrict__ depth_w,         // [128][9]
    const float* __restrict__ depth_b,         // [128]
    unsigned int* __restrict__ ybuf,           // [NCH][L/2] bf16 l-pairs
    float* __restrict__ gsum, float* __restrict__ gsq,
    const float* __restrict__ gamma, const float* __restrict__ beta,
    float* __restrict__ out,                   // [Q*NCH][16384]
    int mode)
{
    __shared__ float dwl[KS][16];   // [k][ch-in-group]
    __shared__ float dbl[16];
    __shared__ float redx[4][4][8]; // [wave][qt][quantity]
    __shared__ __align__(16) unsigned short ytile[16][264]; // [ch][l], pad 264

    const int tid  = threadIdx.x;
    const int lane = tid & 63;
    const int wave = tid >> 6;
    const int g = blockIdx.x & 7;
    const int qt = lane & 3;        // 8-byte chunk of 32-B row
    const int lq = lane >> 2;       // l within batch of 16

    // ================= Phase A: gather =================
    if (mode != 1) {
        if (tid < 144) {
            int k = tid >> 4, ch = tid & 15;
            dwl[k][ch] = depth_w[(g * 16 + ch) * KS + k];
        }
        if (tid < 16) dbl[tid] = depth_b[g * 16 + tid];
        __syncthreads();

        f32x2 dw[KS][2];
        #pragma unroll
        for (int k = 0; k < KS; ++k) {
            f32x4 t = *(const f32x4*)&dwl[k][qt * 4];
            dw[k][0].x = t.x; dw[k][0].y = t.y;
            dw[k][1].x = t.z; dw[k][1].y = t.w;
        }
        f32x2 db01, db23;
        {
            f32x4 t = *(const f32x4*)&dbl[qt * 4];
            db01.x = t.x; db01.y = t.y; db23.x = t.z; db23.y = t.w;
        }

        const unsigned int* slab = xT + ((size_t)g << 20);        // g*HW*8

        f32x2 sum01 = {0.f, 0.f}, sum23 = {0.f, 0.f};
        f32x2 sq01  = {0.f, 0.f}, sq23  = {0.f, 0.f};

        for (int t = 0; t < 5; ++t) {
            const int base_l = ((blockIdx.x >> 3) + t * 128) * LPB;

            #pragma unroll
            for (int bq = 0; bq < 4; ++bq) {
                const int lloc = wave * 64 + bq * 16 + lq;  // local l in [0,256)
                const unsigned int* rp = rec + (size_t)(base_l + lloc) * 12;
                const u32x4 r0 = __builtin_nontemporal_load((const u32x4*)rp);
                const u32x4 r1 = __builtin_nontemporal_load((const u32x4*)(rp + 4));
                const unsigned int r8 = __builtin_nontemporal_load(rp + 8);
                const unsigned int rr[KS] = {r0.x, r0.y, r0.z, r0.w,
                                             r1.x, r1.y, r1.z, r1.w, r8};

                u32x2 pv[KS];
                #pragma unroll
                for (int k = 0; k < KS; ++k)
                    pv[k] = *(const u32x2*)(slab + ((rr[k] & 0x1FFFFu) << 3) + (qt << 1));

                f32x2 acc01 = db01, acc23 = db23;
                #pragma unroll
                for (int k = 0; k < KS; ++k) {
                    const float mk = fmaf((float)(rr[k] >> 17), 3.0517578125e-5f, 1.0f);
                    f32x2 mk2; mk2.x = mk; mk2.y = mk;
                    f32x2 xa; xa.x = bflo(pv[k].x); xa.y = bfhi(pv[k].x);
                    f32x2 xb; xb.x = bflo(pv[k].y); xb.y = bfhi(pv[k].y);
                    acc01 = __builtin_elementwise_fma(xa * mk2, dw[k][0], acc01);
                    acc23 = __builtin_elementwise_fma(xb * mk2, dw[k][1], acc23);
                }

                ytile[qt * 4 + 0][lloc] = f2bf(acc01.x);
                ytile[qt * 4 + 1][lloc] = f2bf(acc01.y);
                ytile[qt * 4 + 2][lloc] = f2bf(acc23.x);
                ytile[qt * 4 + 3][lloc] = f2bf(acc23.y);

                sum01 += acc01; sum23 += acc23;
                sq01 = __builtin_elementwise_fma(acc01, acc01, sq01);
                sq23 = __builtin_elementwise_fma(acc23, acc23, sq23);
            }

            __syncthreads();   // ytile complete

            // flush: 16 channels x 512 B contiguous (full-line stores)
            {
                const int ch = tid >> 4;
                const int m  = tid & 15;
                const u32x4 v0 = *(const u32x4*)&ytile[ch][m * 16];
                const u32x4 v1 = *(const u32x4*)&ytile[ch][m * 16 + 8];
                unsigned int* dst = ybuf + (size_t)(g * 16 + ch) * (L_TOTAL / 2)
                                  + (base_l >> 1) + m * 8;
                *(u32x4*)dst = v0;
                *(u32x4*)(dst + 4) = v1;
            }
            __syncthreads();   // ytile reusable
        }

        // stats reduction over lq (lane bits 2..5) via butterfly shuffles
        #pragma unroll
        for (int s = 4; s <= 32; s <<= 1) {
            sum01.x += __shfl_xor(sum01.x, s);
            sum01.y += __shfl_xor(sum01.y, s);
            sum23.x += __shfl_xor(sum23.x, s);
            sum23.y += __shfl_xor(sum23.y, s);
            sq01.x  += __shfl_xor(sq01.x,  s);
            sq01.y  += __shfl_xor(sq01.y,  s);
            sq23.x  += __shfl_xor(sq23.x,  s);
            sq23.y  += __shfl_xor(sq23.y,  s);
        }
        if (lane < 4) {
            float* rw = &redx[wave][lane][0];
            rw[0] = sum01.x; rw[1] = sum01.y; rw[2] = sum23.x; rw[3] = sum23.y;
            rw[4] = sq01.x;  rw[5] = sq01.y;  rw[6] = sq23.x;  rw[7] = sq23.y;
        }
        __syncthreads();
        if (tid < 32) {
            const int q = tid >> 2, qq = tid & 3;
            float s = redx[0][qq][q] + redx[1][qq][q] + redx[2][qq][q] + redx[3][qq][q];
            const int ch = g * 16 + qq * 4 + (q & 3);
            float* dst = (q >= 4) ? gsq : gsum;
            atomicAdd(&dst[ch], s);
        }
    }

    if (mode == 2)
        cooperative_groups_ns::this_grid().sync();  // stats + ybuf visible

    // ================= Phase B: finalize =================
    if (mode != 0) {
        const float invN = 1.0f / (float)L_TOTAL;
        const int r = blockIdx.x >> 3;
        #pragma unroll
        for (int pass = 0; pass < 2; ++pass) {
            const int rr2 = r + pass * 128;
            if (rr2 < 160) {                   // 160 (q,cc) pairs per group
                const int q = rr2 >> 4;
                const int c = g * 16 + (rr2 & 15);
                const float m = gsum[c] * invN;
                const float var = gsq[c] * invN - m * m;
                const float sc = gamma[c] * rsqrtf(var + 1e-5f);
                const float sh = beta[c] - m * sc;

                const u32x4* src = (const u32x4*)ybuf + (size_t)c * (L_TOTAL / 8)
                                 + (size_t)q * 2048;
                float* dst = out + ((size_t)(q * NCH + c) << 14);

                #pragma unroll 2
                for (int it = 0; it < 8; ++it) {
                    const int i = it * 256 + tid;
                    const u32x4 v = src[i];
                    f32x4 o0, o1;
                    float z;
                    z = fmaf(bflo(v.x), sc, sh); o0.x = z / (1.0f + __expf(-z));
                    z = fmaf(bfhi(v.x), sc, sh); o0.y = z / (1.0f + __expf(-z));
                    z = fmaf(bflo(v.y), sc, sh); o0.z = z / (1.0f + __expf(-z));
                    z = fmaf(bfhi(v.y), sc, sh); o0.w = z / (1.0f + __expf(-z));
                    z = fmaf(bflo(v.z), sc, sh); o1.x = z / (1.0f + __expf(-z));
                    z = fmaf(bfhi(v.z), sc, sh); o1.y = z / (1.0f + __expf(-z));
                    z = fmaf(bflo(v.w), sc, sh); o1.z = z / (1.0f + __expf(-z));
                    z = fmaf(bfhi(v.w), sc, sh); o1.w = z / (1.0f + __expf(-z));
                    *(f32x4*)&dst[i * 8 + 0] = o0;
                    *(f32x4*)&dst[i * 8 + 4] = o1;
                }
            }
        }
    }
}

extern "C" void kernel_launch(void* const* d_in, const int* in_sizes, int n_in,
                              void* d_out, int out_size, void* d_ws, size_t ws_size,
                              hipStream_t stream) {
    const f32x4* x_f4  = (const f32x4*)d_in[0];
    const int* cks     = (const int*)d_in[1];
    const float* aw    = (const float*)d_in[2];
    const float* ab    = (const float*)d_in[3];
    const float* dw    = (const float*)d_in[4];
    const float* db    = (const float*)d_in[5];
    const float* gm    = (const float*)d_in[6];
    const float* bt    = (const float*)d_in[7];

    char* ws = (char*)d_ws;
    unsigned int* xT   = (unsigned int*)ws;                  // 33,554,432 B
    float2* meanmaxP   = (float2*)(ws + 33554432);           // 1,048,576 B
    unsigned int* ybuf = (unsigned int*)(ws + 34603008);     // 41,943,040 B
    unsigned int* rec  = (unsigned int*)(ws + 76546048);     // 7,864,320 B
    float* gsum        = (float*)(ws + 84410368);            // 512 B
    float* gsq         = gsum + NCH;                         // 512 B
    float* outp        = (float*)d_out;

    int mode2 = 2;
    void* argsP[] = {(void*)&x_f4, (void*)&xT, (void*)&meanmaxP, (void*)&cks,
                     (void*)&aw, (void*)&ab, (void*)&rec, (void*)&gsum,
                     (void*)&mode2};
    hipError_t e = hipLaunchCooperativeKernel((void*)prep_kernel,
                                              dim3(512), dim3(256),
                                              argsP, 0, stream);
    if (e == hipSuccess) {
        void* argsG[] = {(void*)&xT, (void*)&rec, (void*)&dw, (void*)&db,
                         (void*)&ybuf, (void*)&gsum, (void*)&gsq,
                         (void*)&gm, (void*)&bt, (void*)&outp, (void*)&mode2};
        e = hipLaunchCooperativeKernel((void*)gatherfin_kernel,
                                       dim3(1024), dim3(256),
                                       argsG, 0, stream);
        if (e == hipSuccess) return;
        // gatherfin coop rejected: phase-split fallback for second half
        gatherfin_kernel<<<1024, 256, 0, stream>>>(
            xT, rec, dw, db, ybuf, gsum, gsq, gm, bt, outp, 0);
        gatherfin_kernel<<<1024, 256, 0, stream>>>(
            xT, rec, dw, db, ybuf, gsum, gsq, gm, bt, outp, 1);
        return;
    }

    // full fallback: phase-split regular launches (round-8-equivalent)
    prep_kernel<<<512, 256, 0, stream>>>(x_f4, xT, meanmaxP, cks, aw, ab, rec, gsum, 0);
    prep_kernel<<<512, 256, 0, stream>>>(x_f4, xT, meanmaxP, cks, aw, ab, rec, gsum, 1);
    gatherfin_kernel<<<1024, 256, 0, stream>>>(
        xT, rec, dw, db, ybuf, gsum, gsq, gm, bt, outp, 0);
    gatherfin_kernel<<<1024, 256, 0, stream>>>(
        xT, rec, dw, db, ybuf, gsum, gsq, gm, bt, outp, 1);
}